// Round 1
// baseline (275.159 us; speedup 1.0000x reference)
//
#include <hip/hip_runtime.h>

#define NT 256

// Kernel A: per-block (256-element tile) sum of seq_lengths.
__global__ __launch_bounds__(NT) void sum_kernel(const int* __restrict__ seq,
                                                 unsigned* __restrict__ blockSums,
                                                 int n) {
    __shared__ unsigned red[NT];
    int tid = threadIdx.x;
    int gid = blockIdx.x * NT + tid;
    unsigned L = (gid < n) ? (unsigned)seq[gid] : 0u;
    red[tid] = L;
    __syncthreads();
    #pragma unroll
    for (int s = NT / 2; s > 0; s >>= 1) {
        if (tid < s) red[tid] += red[tid + s];
        __syncthreads();
    }
    if (tid == 0) blockSums[blockIdx.x] = red[0];
}

// Kernel B: single-block sequential-chunked exclusive scan of block sums.
__global__ __launch_bounds__(NT) void scan_kernel(const unsigned* __restrict__ blockSums,
                                                  unsigned* __restrict__ blockOffsets,
                                                  int nb) {
    __shared__ unsigned sdata[NT];
    int tid = threadIdx.x;
    unsigned carry = 0;
    for (int base = 0; base < nb; base += NT) {
        int i = base + tid;
        unsigned v = (i < nb) ? blockSums[i] : 0u;
        sdata[tid] = v;
        __syncthreads();
        for (int off = 1; off < NT; off <<= 1) {
            unsigned add = (tid >= off) ? sdata[tid - off] : 0u;
            __syncthreads();
            sdata[tid] += add;
            __syncthreads();
        }
        unsigned incl = sdata[tid];
        if (i < nb) blockOffsets[i] = incl - v + carry;
        unsigned tot = sdata[NT - 1];
        __syncthreads();
        carry += tot;
    }
}

// Kernel C: main compute + ordered compaction.
__global__ __launch_bounds__(NT) void main_kernel(const float* __restrict__ xss,
                                                  const int* __restrict__ seq,
                                                  const float* __restrict__ Wcob,
                                                  const float* __restrict__ Wreg,
                                                  const unsigned* __restrict__ blockOffsets,
                                                  float* __restrict__ out,
                                                  int n) {
    __shared__ unsigned sscan[NT];
    int tid = threadIdx.x;
    int gid = blockIdx.x * NT + tid;
    unsigned L = (gid < n) ? (unsigned)seq[gid] : 0u;

    // Block-wide inclusive scan (Hillis-Steele) of L.
    sscan[tid] = L;
    __syncthreads();
    for (int off = 1; off < NT; off <<= 1) {
        unsigned add = (tid >= off) ? sscan[tid - off] : 0u;
        __syncthreads();
        sscan[tid] += add;
        __syncthreads();
    }
    unsigned offset = blockOffsets[blockIdx.x] + sscan[tid] - L;  // exclusive

    if (gid >= n) return;

    // Load this element's 20 floats: 5 aligned float4s (80B, 16B-aligned).
    const float* p = xss + (size_t)gid * 20;
    float4 v0 = *(const float4*)(p + 0);
    float4 v1 = *(const float4*)(p + 4);
    float4 v2 = *(const float4*)(p + 8);
    float4 v3 = *(const float4*)(p + 12);
    float4 v4 = *(const float4*)(p + 16);
    float x[20];
    x[0]=v0.x;  x[1]=v0.y;  x[2]=v0.z;  x[3]=v0.w;
    x[4]=v1.x;  x[5]=v1.y;  x[6]=v1.z;  x[7]=v1.w;
    x[8]=v2.x;  x[9]=v2.y;  x[10]=v2.z; x[11]=v2.w;
    x[12]=v3.x; x[13]=v3.y; x[14]=v3.z; x[15]=v3.w;
    x[16]=v4.x; x[17]=v4.y; x[18]=v4.z; x[19]=v4.w;

    // Uniform-address weight loads -> scalar loads (SGPRs).
    float wc[16], wr[16];
    #pragma unroll
    for (int i = 0; i < 16; i++) { wc[i] = Wcob[i]; wr[i] = Wreg[i]; }

    // bs[s][c] = sum_f fs[s][f] * Wcob[c][f]   (fs[s][f] = x[s*5+1+f])
    float bs[4][4];
    #pragma unroll
    for (int s = 0; s < 4; s++) {
        #pragma unroll
        for (int c = 0; c < 4; c++) {
            float acc = 0.f;
            #pragma unroll
            for (int f = 0; f < 4; f++) acc += x[s * 5 + 1 + f] * wc[c * 4 + f];
            bs[s][c] = acc;
        }
    }

    // context[c] = sum_{s<L} bs[s][c] * scale[s]   (scale[s] = x[s*5])
    float ctx[4] = {0.f, 0.f, 0.f, 0.f};
    #pragma unroll
    for (int s = 0; s < 4; s++) {
        float m = (s < (int)L) ? x[s * 5] : 0.f;
        #pragma unroll
        for (int c = 0; c < 4; c++) ctx[c] += bs[s][c] * m;
    }

    // ys[m] = sum_c context[c] * Wreg[m][c]
    float ys[4];
    #pragma unroll
    for (int m = 0; m < 4; m++) {
        float acc = 0.f;
        #pragma unroll
        for (int c = 0; c < 4; c++) acc += ctx[c] * wr[m * 4 + c];
        ys[m] = acc;
    }

    // projs[s] = sum_m bs[s][m] * ys[m], written compacted for s < L.
    #pragma unroll
    for (int s = 0; s < 4; s++) {
        if (s < (int)L) {
            float acc = 0.f;
            #pragma unroll
            for (int m = 0; m < 4; m++) acc += bs[s][m] * ys[m];
            out[offset + s] = acc;
        }
    }
}

extern "C" void kernel_launch(void* const* d_in, const int* in_sizes, int n_in,
                              void* d_out, int out_size, void* d_ws, size_t ws_size,
                              hipStream_t stream) {
    const float* xss  = (const float*)d_in[0];
    const int*   seq  = (const int*)d_in[1];
    const float* Wcob = (const float*)d_in[2];
    const float* Wreg = (const float*)d_in[3];
    float* out = (float*)d_out;

    int n  = in_sizes[1];            // B
    int nb = (n + NT - 1) / NT;      // number of 256-element tiles

    unsigned* blockSums    = (unsigned*)d_ws;
    unsigned* blockOffsets = blockSums + nb;

    sum_kernel<<<nb, NT, 0, stream>>>(seq, blockSums, n);
    scan_kernel<<<1, NT, 0, stream>>>(blockSums, blockOffsets, nb);
    main_kernel<<<nb, NT, 0, stream>>>(xss, seq, Wcob, Wreg, blockOffsets, out, n);
}

// Round 2
// 243.678 us; speedup vs baseline: 1.1292x; 1.1292x over previous
//
#include <hip/hip_runtime.h>

#define NT 256

// Kernel A: per-block (256-element tile) sum of seq_lengths via wave reduce.
__global__ __launch_bounds__(NT) void sum_kernel(const int* __restrict__ seq,
                                                 unsigned* __restrict__ blockSums,
                                                 int n) {
    __shared__ unsigned wsum[4];
    int tid = threadIdx.x;
    int gid = blockIdx.x * NT + tid;
    int lane = tid & 63, wave = tid >> 6;
    unsigned v = (gid < n) ? (unsigned)seq[gid] : 0u;
    #pragma unroll
    for (int off = 32; off > 0; off >>= 1) v += __shfl_down(v, off);
    if (lane == 0) wsum[wave] = v;
    __syncthreads();
    if (tid == 0) blockSums[blockIdx.x] = wsum[0] + wsum[1] + wsum[2] + wsum[3];
}

// Shared helper pattern: block-wide exclusive scan (shfl intra-wave + LDS cross-wave).
__device__ __forceinline__ unsigned block_excl_scan(unsigned v_in, int tid,
                                                    unsigned* wtot /*[4] LDS*/,
                                                    unsigned* block_total) {
    int lane = tid & 63, wave = tid >> 6;
    unsigned v = v_in;
    #pragma unroll
    for (int off = 1; off < 64; off <<= 1) {
        unsigned t = __shfl_up(v, off);
        if (lane >= off) v += t;
    }
    if (lane == 63) wtot[wave] = v;
    __syncthreads();
    unsigned woff = 0;
    #pragma unroll
    for (int w = 0; w < 4; w++) woff += (w < wave) ? wtot[w] : 0u;
    if (block_total) *block_total = wtot[0] + wtot[1] + wtot[2] + wtot[3];
    return woff + v - v_in;  // exclusive
}

// Kernel B1: each block scans 256 contiguous blockSums -> group-exclusive
// offsets; writes group total.
__global__ __launch_bounds__(NT) void group_scan_kernel(const unsigned* __restrict__ blockSums,
                                                        unsigned* __restrict__ blockOffsets,
                                                        unsigned* __restrict__ groupSums,
                                                        int nb) {
    __shared__ unsigned wtot[4];
    int tid = threadIdx.x;
    int i = blockIdx.x * NT + tid;
    unsigned v = (i < nb) ? blockSums[i] : 0u;
    unsigned total;
    unsigned excl = block_excl_scan(v, tid, wtot, &total);
    if (i < nb) blockOffsets[i] = excl;
    if (tid == 0) groupSums[blockIdx.x] = total;
}

// Kernel B2: one wave scans the (<=64) group totals -> exclusive group offsets.
__global__ __launch_bounds__(64) void top_scan_kernel(const unsigned* __restrict__ groupSums,
                                                      unsigned* __restrict__ groupOffsets,
                                                      int ng) {
    int tid = threadIdx.x;
    unsigned v = (tid < ng) ? groupSums[tid] : 0u;
    unsigned incl = v;
    #pragma unroll
    for (int off = 1; off < 64; off <<= 1) {
        unsigned t = __shfl_up(incl, off);
        if (tid >= off) incl += t;
    }
    if (tid < ng) groupOffsets[tid] = incl - v;
}

// Kernel C: main compute + ordered compaction.
__global__ __launch_bounds__(NT) void main_kernel(const float* __restrict__ xss,
                                                  const int* __restrict__ seq,
                                                  const float* __restrict__ Wcob,
                                                  const float* __restrict__ Wreg,
                                                  const unsigned* __restrict__ blockOffsets,
                                                  const unsigned* __restrict__ groupOffsets,
                                                  float* __restrict__ out,
                                                  int n) {
    __shared__ unsigned wtot[4];
    int tid = threadIdx.x;
    int gid = blockIdx.x * NT + tid;
    unsigned L = (gid < n) ? (unsigned)seq[gid] : 0u;

    unsigned excl = block_excl_scan(L, tid, wtot, nullptr);
    unsigned offset = groupOffsets[blockIdx.x >> 8] + blockOffsets[blockIdx.x] + excl;

    if (gid >= n) return;

    // Load this element's 20 floats: 5 aligned float4s (80B, 16B-aligned).
    const float* p = xss + (size_t)gid * 20;
    float4 v0 = *(const float4*)(p + 0);
    float4 v1 = *(const float4*)(p + 4);
    float4 v2 = *(const float4*)(p + 8);
    float4 v3 = *(const float4*)(p + 12);
    float4 v4 = *(const float4*)(p + 16);
    float x[20];
    x[0]=v0.x;  x[1]=v0.y;  x[2]=v0.z;  x[3]=v0.w;
    x[4]=v1.x;  x[5]=v1.y;  x[6]=v1.z;  x[7]=v1.w;
    x[8]=v2.x;  x[9]=v2.y;  x[10]=v2.z; x[11]=v2.w;
    x[12]=v3.x; x[13]=v3.y; x[14]=v3.z; x[15]=v3.w;
    x[16]=v4.x; x[17]=v4.y; x[18]=v4.z; x[19]=v4.w;

    // Uniform-address weight loads -> scalar loads.
    float wc[16], wr[16];
    #pragma unroll
    for (int i = 0; i < 16; i++) { wc[i] = Wcob[i]; wr[i] = Wreg[i]; }

    // bs[s][c] = sum_f fs[s][f] * Wcob[c][f]
    float bs[4][4];
    #pragma unroll
    for (int s = 0; s < 4; s++) {
        #pragma unroll
        for (int c = 0; c < 4; c++) {
            float acc = 0.f;
            #pragma unroll
            for (int f = 0; f < 4; f++) acc += x[s * 5 + 1 + f] * wc[c * 4 + f];
            bs[s][c] = acc;
        }
    }

    // context[c] = sum_{s<L} bs[s][c] * scale[s]
    float ctx[4] = {0.f, 0.f, 0.f, 0.f};
    #pragma unroll
    for (int s = 0; s < 4; s++) {
        float m = (s < (int)L) ? x[s * 5] : 0.f;
        #pragma unroll
        for (int c = 0; c < 4; c++) ctx[c] += bs[s][c] * m;
    }

    // ys[m] = sum_c context[c] * Wreg[m][c]
    float ys[4];
    #pragma unroll
    for (int m = 0; m < 4; m++) {
        float acc = 0.f;
        #pragma unroll
        for (int c = 0; c < 4; c++) acc += ctx[c] * wr[m * 4 + c];
        ys[m] = acc;
    }

    // projs[s] = sum_m bs[s][m] * ys[m], compacted for s < L.
    #pragma unroll
    for (int s = 0; s < 4; s++) {
        if (s < (int)L) {
            float acc = 0.f;
            #pragma unroll
            for (int m = 0; m < 4; m++) acc += bs[s][m] * ys[m];
            out[offset + s] = acc;
        }
    }
}

extern "C" void kernel_launch(void* const* d_in, const int* in_sizes, int n_in,
                              void* d_out, int out_size, void* d_ws, size_t ws_size,
                              hipStream_t stream) {
    const float* xss  = (const float*)d_in[0];
    const int*   seq  = (const int*)d_in[1];
    const float* Wcob = (const float*)d_in[2];
    const float* Wreg = (const float*)d_in[3];
    float* out = (float*)d_out;

    int n  = in_sizes[1];            // B = 2,000,000
    int nb = (n + NT - 1) / NT;      // 7813 tiles
    int ng = (nb + NT - 1) / NT;     // 31 groups (must be <= 64 for top scan)

    unsigned* blockSums    = (unsigned*)d_ws;
    unsigned* blockOffsets = blockSums + nb;
    unsigned* groupSums    = blockOffsets + nb;
    unsigned* groupOffsets = groupSums + ng;

    sum_kernel<<<nb, NT, 0, stream>>>(seq, blockSums, n);
    group_scan_kernel<<<ng, NT, 0, stream>>>(blockSums, blockOffsets, groupSums, nb);
    top_scan_kernel<<<1, 64, 0, stream>>>(groupSums, groupOffsets, ng);
    main_kernel<<<nb, NT, 0, stream>>>(xss, seq, Wcob, Wreg, blockOffsets, groupOffsets, out, n);
}